// Round 1
// baseline (1755.598 us; speedup 1.0000x reference)
//
#include <hip/hip_runtime.h>

// Problem constants
#define B_   4
#define C_   128
#define HIN  512     // input H=W
#define HO   128     // resized h=w
#define HP   136     // padded h+2K
#define EPSF 1e-8f

// Workspace layout (in floats)
#define OFF_XR 0UL            // (4,128,128,128)  8,388,608
#define OFF_YP 8388608UL      // (4,128,136,136)  9,469,952
#define OFF_YC 17858560UL     // (4,128,136,136)  9,469,952
#define OFF_NX 27328512UL     // (4,4,128,128)      262,144
#define OFF_NY 27590656UL     // (4,4,136,136)      295,936
// total floats 27,886,592 -> ~111.5 MB workspace

// ---------------------------------------------------------------------------
// Bilinear resize 512x512 -> 128x128, align_corners
// ---------------------------------------------------------------------------
__global__ __launch_bounds__(256) void k_resize(const float* __restrict__ in,
                                                float* __restrict__ o) {
  int gid = blockIdx.x * 256 + threadIdx.x;           // over 4*128*128*128
  int ox = gid & 127;
  int oy = (gid >> 7) & 127;
  size_t bc = (size_t)(gid >> 14);
  const float S = 511.0f / 127.0f;
  float fy = oy * S, fx = ox * S;
  int y0 = (int)fy, x0 = (int)fx;
  float wy = fy - (float)y0, wx = fx - (float)x0;
  int y1 = min(y0 + 1, 511), x1 = min(x0 + 1, 511);
  const float* p = in + bc * (size_t)(HIN * HIN);
  float v00 = p[y0 * HIN + x0], v01 = p[y0 * HIN + x1];
  float v10 = p[y1 * HIN + x0], v11 = p[y1 * HIN + x1];
  o[gid] = (1.f - wy) * ((1.f - wx) * v00 + wx * v01)
         +        wy  * ((1.f - wx) * v10 + wx * v11);
}

// Resize + reflect pad K=4: output (4,128,136,136)
__global__ __launch_bounds__(256) void k_resize_pad(const float* __restrict__ in,
                                                    float* __restrict__ o) {
  int gid = blockIdx.x * 256 + threadIdx.x;           // over 4*128*136*136
  int px = gid % HP;
  int tmp = gid / HP;
  int py = tmp % HP;
  size_t bc = (size_t)(tmp / HP);
  int iy = py - 4, ix = px - 4;
  iy = iy < 0 ? -iy : (iy > 127 ? 254 - iy : iy);
  ix = ix < 0 ? -ix : (ix > 127 ? 254 - ix : ix);
  const float S = 511.0f / 127.0f;
  float fy = iy * S, fx = ix * S;
  int y0 = (int)fy, x0 = (int)fx;
  float wy = fy - (float)y0, wx = fx - (float)x0;
  int y1 = min(y0 + 1, 511), x1 = min(x0 + 1, 511);
  const float* p = in + bc * (size_t)(HIN * HIN);
  float v00 = p[y0 * HIN + x0], v01 = p[y0 * HIN + x1];
  float v10 = p[y1 * HIN + x0], v11 = p[y1 * HIN + x1];
  o[gid] = (1.f - wy) * ((1.f - wx) * v00 + wx * v01)
         +        wy  * ((1.f - wx) * v10 + wx * v11);
}

// ---------------------------------------------------------------------------
// 3x3 conv, 128->128 ch, zero pad 1, on 136x136. Tile: 8x16 spatial x 32 co.
// Thread: 4 co x (2x2) px. 256 threads/block.
// ---------------------------------------------------------------------------
__global__ __launch_bounds__(256) void k_conv(const float* __restrict__ yp,
                                              const float* __restrict__ Wt,
                                              const float* __restrict__ bias,
                                              float* __restrict__ yc) {
  __shared__ float sIm[8][10][18];   // 8 ci x (8+2) x (16+2)
  __shared__ float sW[32][8][12];    // 32 co x 8 ci x 9 (pad 12 for b128)
  const int t = threadIdx.x;
  const int bx = blockIdx.x, by = blockIdx.y;
  const int b = blockIdx.z >> 2, cot = blockIdx.z & 3;
  const int cq = t >> 5;                 // 0..7 co-quad
  const int pq = t & 31;                 // 32 pixel-quads
  const int px0 = (pq & 7) * 2;
  const int py0 = (pq >> 3) * 2;
  float acc[4][4];
#pragma unroll
  for (int i = 0; i < 4; i++)
#pragma unroll
    for (int j = 0; j < 4; j++) acc[i][j] = 0.f;

  const float* ypb = yp + (size_t)b * C_ * (HP * HP);

  for (int ci0 = 0; ci0 < C_; ci0 += 8) {
    // stage input tile (zero-padded at conv border)
    for (int i = t; i < 8 * 10 * 18; i += 256) {
      int ci = i / 180, rem = i % 180;
      int r = rem / 18, c = rem % 18;
      int gy = by * 8 - 1 + r;
      int gx = bx * 16 - 1 + c;
      float v = 0.f;
      if ((unsigned)gy < HP && (unsigned)gx < HP)
        v = ypb[(size_t)(ci0 + ci) * (HP * HP) + gy * HP + gx];
      sIm[ci][r][c] = v;
    }
    // stage weights
    for (int i = t; i < 32 * 8 * 9; i += 256) {
      int co = i / 72, rem = i % 72;
      int ci = rem / 9, k = rem % 9;
      sW[co][ci][k] = Wt[((size_t)(cot * 32 + co) * C_ + (ci0 + ci)) * 9 + k];
    }
    __syncthreads();
#pragma unroll
    for (int ci = 0; ci < 8; ci++) {
      float im[4][4];
#pragma unroll
      for (int r = 0; r < 4; r++)
#pragma unroll
        for (int c = 0; c < 4; c++) im[r][c] = sIm[ci][py0 + r][px0 + c];
#pragma unroll
      for (int cc = 0; cc < 4; cc++) {
        const float* wp = &sW[cq * 4 + cc][ci][0];
        float w0 = wp[0], w1 = wp[1], w2 = wp[2];
        float w3 = wp[3], w4 = wp[4], w5 = wp[5];
        float w6 = wp[6], w7 = wp[7], w8 = wp[8];
#pragma unroll
        for (int iy = 0; iy < 2; iy++)
#pragma unroll
          for (int ix = 0; ix < 2; ix++)
            acc[cc][iy * 2 + ix] +=
                w0 * im[iy][ix]     + w1 * im[iy][ix + 1]     + w2 * im[iy][ix + 2] +
                w3 * im[iy + 1][ix] + w4 * im[iy + 1][ix + 1] + w5 * im[iy + 1][ix + 2] +
                w6 * im[iy + 2][ix] + w7 * im[iy + 2][ix + 1] + w8 * im[iy + 2][ix + 2];
      }
    }
    __syncthreads();
  }
  const int co0 = cot * 32 + cq * 4;
#pragma unroll
  for (int cc = 0; cc < 4; cc++) {
    float bv = bias[co0 + cc];
#pragma unroll
    for (int iy = 0; iy < 2; iy++)
#pragma unroll
      for (int ix = 0; ix < 2; ix++) {
        int gy = by * 8 + py0 + iy;
        int gx = bx * 16 + px0 + ix;
        if (gx < HP)
          yc[((size_t)(b * C_ + co0 + cc) * HP + gy) * HP + gx] =
              acc[cc][iy * 2 + ix] + bv;
      }
  }
}

// ---------------------------------------------------------------------------
// Group norms
// ---------------------------------------------------------------------------
__global__ __launch_bounds__(256) void k_normx(const float* __restrict__ xr,
                                               float* __restrict__ nxp) {
  int gid = blockIdx.x * 256 + threadIdx.x;           // 4*4*128*128
  int pix = gid & 16383;
  int bg = gid >> 14;
  int b = bg >> 2, g = bg & 3;
  const float* p = xr + (size_t)(b * C_ + g * 32) * 16384 + pix;
  float s = 0.f;
#pragma unroll
  for (int c = 0; c < 32; c++) {
    float v = p[(size_t)c * 16384];
    s += v * v;
  }
  nxp[gid] = fmaxf(sqrtf(s), EPSF);
}

__global__ __launch_bounds__(256) void k_normy(const float* __restrict__ yc,
                                               float* __restrict__ nyp) {
  int gid = blockIdx.x * 256 + threadIdx.x;           // 4*4*136*136
  int pix = gid % (HP * HP);
  int bg = gid / (HP * HP);
  int b = bg >> 2, g = bg & 3;
  const float* p = yc + (size_t)(b * C_ + g * 32) * (HP * HP) + pix;
  float s = 0.f;
#pragma unroll
  for (int c = 0; c < 32; c++) {
    float v = p[(size_t)c * (HP * HP)];
    s += v * v;
  }
  nyp[gid] = fmaxf(sqrtf(s), EPSF);
}

// ---------------------------------------------------------------------------
// Correlation: out[b,g,81,128,128]. Block: 16x8 px tile for one (b,g).
// y tile (16 rows x 24 cols x 32 ch) in LDS c-fastest (pad 36), x in regs.
// ---------------------------------------------------------------------------
__global__ __launch_bounds__(128) void k_corr(const float* __restrict__ xr,
                                              const float* __restrict__ yc,
                                              const float* __restrict__ nxp,
                                              const float* __restrict__ nyp,
                                              float* __restrict__ out) {
  __shared__ float sY[16][24][36];
  __shared__ float sNy[16][24];
  const int t = threadIdx.x;
  const int bg = blockIdx.z;
  const int b = bg >> 2, g = bg & 3;
  const int tx = blockIdx.x * 16;
  const int ty = blockIdx.y * 8;
  const float* ycb = yc + (size_t)(b * C_ + g * 32) * (HP * HP);

  for (int i = t; i < 16 * 24; i += 128) {
    int py = i / 24, px = i % 24;
    sNy[py][px] = nyp[((size_t)bg * HP + (ty + py)) * HP + (tx + px)];
  }
  for (int c = 0; c < 32; c++) {
    for (int i = t; i < 16 * 24; i += 128) {
      int py = i / 24, px = i % 24;
      sY[py][px][c] = ycb[(size_t)c * (HP * HP) + (size_t)(ty + py) * HP + (tx + px)];
    }
  }
  __syncthreads();

  const int py = t >> 4, px = t & 15;
  float4 xv[8];
  const float* xb = xr + (size_t)(b * C_ + g * 32) * 16384
                       + (size_t)(ty + py) * HO + (tx + px);
#pragma unroll
  for (int c8 = 0; c8 < 8; c8++) {
    xv[c8].x = xb[(size_t)(c8 * 4 + 0) * 16384];
    xv[c8].y = xb[(size_t)(c8 * 4 + 1) * 16384];
    xv[c8].z = xb[(size_t)(c8 * 4 + 2) * 16384];
    xv[c8].w = xb[(size_t)(c8 * 4 + 3) * 16384];
  }
  const float nxv = nxp[((size_t)bg * HO + (ty + py)) * HO + (tx + px)];
  float* ob = out + (size_t)bg * 81 * 16384 + (size_t)(ty + py) * HO + (tx + px);

#pragma unroll 1
  for (int dy = 0; dy < 9; dy++) {
#pragma unroll 1
    for (int dx = 0; dx < 9; dx++) {
      float dot = 0.f;
#pragma unroll
      for (int c8 = 0; c8 < 8; c8++) {
        const float4 yv = *(const float4*)&sY[py + dy][px + dx][c8 * 4];
        dot += xv[c8].x * yv.x + xv[c8].y * yv.y
             + xv[c8].z * yv.z + xv[c8].w * yv.w;
      }
      float denom = nxv * sNy[py + dy][px + dx];
      ob[(size_t)(dy * 9 + dx) * 16384] = dot / denom;
    }
  }
}

// ---------------------------------------------------------------------------
extern "C" void kernel_launch(void* const* d_in, const int* in_sizes, int n_in,
                              void* d_out, int out_size, void* d_ws, size_t ws_size,
                              hipStream_t stream) {
  const float* x     = (const float*)d_in[0];
  const float* y     = (const float*)d_in[1];
  const float* Wt    = (const float*)d_in[2];
  const float* bconv = (const float*)d_in[3];
  float* out = (float*)d_out;
  float* ws  = (float*)d_ws;
  float* xr = ws + OFF_XR;
  float* yp = ws + OFF_YP;
  float* yc = ws + OFF_YC;
  float* nx = ws + OFF_NX;
  float* ny = ws + OFF_NY;

  k_resize<<<8388608 / 256, 256, 0, stream>>>(x, xr);
  k_resize_pad<<<9469952 / 256, 256, 0, stream>>>(y, yp);
  k_conv<<<dim3(9, 17, 16), 256, 0, stream>>>(yp, Wt, bconv, yc);
  k_normx<<<1024, 256, 0, stream>>>(xr, nx);
  k_normy<<<1156, 256, 0, stream>>>(yc, ny);
  k_corr<<<dim3(8, 16, 16), 128, 0, stream>>>(xr, yc, nx, ny, out);
}